// Round 7
// baseline (103.277 us; speedup 1.0000x reference)
//
#include <hip/hip_runtime.h>
#include <math.h>

#define HH 256
#define WW 256
#define NIMG 8            // B*C
#define NF 32             // 8 images * 4 fields
#define FLDSZ (HH * WW)
#define NELEM (NIMG * FLDSZ)
#define LARGE (1 << 27)   // sentinel d^2 when a field has no source pixels at all
#define BIGD (1 << 20)
#define BIGC (1 << 26)    // capped row-dist^2 marker (window miss / row out of range)
#define NBLK 512          // k_dtloss grid size

// ws layout (bitmaps fully written by K0; accumulators zeroed by K0 block 0):
// [0,      64KB)   u64 bmP[8][256][4]   preds fg bitmap
// [64KB,  128KB)   u64 bmT[8][256][4]   targets fg bitmap
// [128KB, +256B)   f64 accA[32]
// [+256B,  +128B)  i32 accM[32]
// [+384B,  +4B)    i32 counter
#define BMP_OFF 0
#define BMT_OFF (64u * 1024)
#define ACA_OFF (128u * 1024)
#define ACM_OFF (ACA_OFF + 256)
#define CNT_OFF (ACA_OFF + 384)

typedef unsigned long long u64;

// ---- K0: per-row 256-bit fg masks for preds and targets + acc zero-init ----
__global__ __launch_bounds__(256) void k_bitmap(
    const float* __restrict__ preds, const float* __restrict__ targets,
    u64* __restrict__ bmP, u64* __restrict__ bmT,
    double* __restrict__ accA, int* __restrict__ accM, int* __restrict__ counter)
{
    const int img = blockIdx.x >> 5;
    const int rg  = blockIdx.x & 31;   // 8-row group
    const int c   = threadIdx.x;
    const int lane = c & 63, wv = c >> 6;

    if (blockIdx.x == 0) {             // zero accumulators (visible to K1 at kernel boundary)
        if (c < NF) { accA[c] = 0.0; accM[c] = 0; }
        if (c == NF) *counter = 0;
    }

    const size_t ibase = ((size_t)img * HH + rg * 8) * WW;
#pragma unroll
    for (int r8 = 0; r8 < 8; ++r8) {
        float pv = preds[ibase + r8 * WW + c];
        float tv = targets[ibase + r8 * WW + c];
        u64 bp = __ballot(pv > 0.0f);   // sigmoid(x)>0.5 <=> x>0
        u64 bt = __ballot(tv > 0.5f);
        if (lane == 0) {
            const int row = rg * 8 + r8;
            bmP[((size_t)img * HH + row) * 4 + wv] = bp;
            bmT[((size_t)img * HH + row) * 4 + wv] = bt;
        }
    }
}

// windowed row-dist^2 for BOTH polarities from one set of 3 words.
// out[0] = sources are set bits (bg field), out[1] = sources are clear bits (fg field)
__device__ __forceinline__ void win_pair(const u64* __restrict__ sm, int j,
                                         int wq, int sh, int out[2])
{
    const u64 cur = sm[j * 4 + wq];
    const u64 lwr = (wq > 0) ? sm[j * 4 + wq - 1] : 0ull;
    const u64 rwr = (wq < 3) ? sm[j * 4 + wq + 1] : 0ull;
#pragma unroll
    for (int pol = 0; pol < 2; ++pol) {
        const u64 cc = pol ? ~cur : cur;
        const u64 lw = pol ? ((wq > 0) ? ~lwr : 0ull) : lwr;
        const u64 rw = pol ? ((wq < 3) ? ~rwr : 0ull) : rwr;
        u64 A = cc >> sh;
        if (sh) A |= rw << (64 - sh);
        int dR = A ? __builtin_ctzll(A) : 1000;
        u64 L = (sh == 63) ? cc : (cc & ((1ull << (sh + 1)) - 1ull));
        int dL;
        if (L)       dL = sh - (63 - __builtin_clzll(L));
        else if (lw) dL = sh + 1 + __builtin_clzll(lw);
        else         dL = 1000;
        int d = min(dR, dL);
        out[pol] = (d <= 255) ? d * d : BIGC;
    }
}

// full-row exact nearest-bit distance with optional inversion
__device__ __forceinline__ int full_rowd_f(const u64* __restrict__ sm, int j,
                                           int c, bool inv)
{
    int bestd = BIGD;
#pragma unroll
    for (int w = 0; w < 4; ++w) {
        u64 mm = sm[j * 4 + w];
        if (inv) mm = ~mm;
        if (!mm) continue;                 // wave-uniform word
        const int base = w * 64;
        int d;
        if (base + 63 < c) {
            d = c - (base + 63 - __builtin_clzll(mm));
        } else if (base > c) {
            d = base + __builtin_ctzll(mm) - c;
        } else {
            const int t = c - base;
            u64 lowm = (t == 63) ? mm : (mm & ((1ull << (t + 1)) - 1ull));
            u64 him  = mm >> t;
            int dl = lowm ? (t - (63 - __builtin_clzll(lowm))) : BIGD;
            int dr = him  ? __builtin_ctzll(him) : BIGD;
            d = min(dl, dr);
        }
        bestd = min(bestd, d);
    }
    return bestd;
}

__device__ __forceinline__ int exact_scan(const u64* __restrict__ sm, int i,
                                          int c, bool inv)
{
    int d0 = full_rowd_f(sm, i, c, inv);
    int eb = (d0 <= 255) ? d0 * d0 : LARGE;
    for (int r = 1; r < HH; ++r) {
        if (__all(r * r >= eb)) break;
        const int jd = i - r, ju = i + r;
        if (jd >= 0) {
            int d = full_rowd_f(sm, jd, c, inv);
            if (d <= 255) eb = min(eb, d * d + r * r);
        }
        if (ju < HH) {
            int d = full_rowd_f(sm, ju, c, inv);
            if (d <= 255) eb = min(eb, d * d + r * r);
        }
    }
    return eb;
}

// ---- K1: fused exact EDT^2 (4 fields) + loss accum + last-block finalize ---
// block = (img, 4-row group): 512 blocks x 256 threads, 16KB LDS.
__global__ __launch_bounds__(256) void k_dtloss(
    const float* __restrict__ preds, const float* __restrict__ targets,
    const u64* __restrict__ bmP, const u64* __restrict__ bmT,
    double* __restrict__ accA, int* __restrict__ accM, int* __restrict__ counter,
    float* __restrict__ out)
{
    const int img = blockIdx.x >> 6;    // 8 images
    const int rg  = blockIdx.x & 63;    // 4-row group
    const int c   = threadIdx.x;
    const int wq  = c >> 6, sh = c & 63;

    __shared__ u64 sp[HH * 4];   // preds fg bitmap (raw)
    __shared__ u64 st[HH * 4];   // targets fg bitmap (raw)

#pragma unroll
    for (int q = 0; q < 4; ++q) {
        sp[q * 256 + c] = bmP[(size_t)img * HH * 4 + q * 256 + c];
        st[q * 256 + c] = bmT[(size_t)img * HH * 4 + q * 256 + c];
    }
    __syncthreads();

    const int i0 = rg * 4;

    float xs[4], ts[4];
#pragma unroll
    for (int ii = 0; ii < 4; ++ii) {
        const size_t idx = ((size_t)img * HH + i0 + ii) * WW + c;
        xs[ii] = preds[idx];
        ts[ii] = targets[idx];
    }

    // rolling 9-row windows: f0=p_fg(inv) f1=p_bg f2=t_fg(inv) f3=t_bg
    int wPf[9], wPb[9], wTf[9], wTb[9];
#pragma unroll
    for (int q = 0; q < 9; ++q) {
        const int j = i0 - 4 + q;
        if ((unsigned)j < HH) {
            int prP[2], prT[2];
            win_pair(sp, j, wq, sh, prP);
            win_pair(st, j, wq, sh, prT);
            wPb[q] = prP[0]; wPf[q] = prP[1];
            wTb[q] = prT[0]; wTf[q] = prT[1];
        } else {
            wPb[q] = BIGC; wPf[q] = BIGC; wTb[q] = BIGC; wTf[q] = BIGC;
        }
    }

    double a0 = 0.0, a1 = 0.0, a2 = 0.0, a3 = 0.0;
    int m0 = 0, m1 = 0, m2 = 0, m3 = 0;

#pragma unroll
    for (int ii = 0; ii < 4; ++ii) {
        const int i = i0 + ii;

#define COMBINE(w) ({                                             \
        int _b = w[4];                                            \
        _b = min(_b, min(w[3], w[5]) + 1);                        \
        _b = min(_b, min(w[2], w[6]) + 4);                        \
        _b = min(_b, min(w[1], w[7]) + 9);                        \
        _b = min(_b, min(w[0], w[8]) + 16); _b; })

        int b0 = COMBINE(wPf);
        int b1 = COMBINE(wPb);
        int b2 = COMBINE(wTf);
        int b3 = COMBINE(wTb);

        if (__any(max(max(b0, b1), max(b2, b3)) > 16)) {   // rare exact fallback
            if (__any(b0 > 16)) b0 = exact_scan(sp, i, c, true);
            if (__any(b1 > 16)) b1 = exact_scan(sp, i, c, false);
            if (__any(b2 > 16)) b2 = exact_scan(st, i, c, true);
            if (__any(b3 > 16)) b3 = exact_scan(st, i, c, false);
        }

        float p   = 1.0f / (1.0f + expf(-xs[ii]));
        float err = (p - ts[ii]) * (p - ts[ii]);
        const double de = (double)err;
        a0 += de * (double)b0;  a1 += de * (double)b1;
        a2 += de * (double)b2;  a3 += de * (double)b3;
        m0 = max(m0, b0); m1 = max(m1, b1); m2 = max(m2, b2); m3 = max(m3, b3);

#pragma unroll
        for (int q = 0; q < 8; ++q) {
            wPf[q] = wPf[q + 1]; wPb[q] = wPb[q + 1];
            wTf[q] = wTf[q + 1]; wTb[q] = wTb[q + 1];
        }
        const int jn = i + 5;
        if ((unsigned)jn < HH) {
            int prP[2], prT[2];
            win_pair(sp, jn, wq, sh, prP);
            win_pair(st, jn, wq, sh, prT);
            wPb[8] = prP[0]; wPf[8] = prP[1];
            wTb[8] = prT[0]; wTf[8] = prT[1];
        } else {
            wPb[8] = BIGC; wPf[8] = BIGC; wTb[8] = BIGC; wTf[8] = BIGC;
        }
    }

    // block reduction (4 waves)
#pragma unroll
    for (int off = 32; off > 0; off >>= 1) {
        a0 += __shfl_down(a0, off); a1 += __shfl_down(a1, off);
        a2 += __shfl_down(a2, off); a3 += __shfl_down(a3, off);
        m0 = max(m0, __shfl_down(m0, off)); m1 = max(m1, __shfl_down(m1, off));
        m2 = max(m2, __shfl_down(m2, off)); m3 = max(m3, __shfl_down(m3, off));
    }
    __shared__ double wA[4][4];
    __shared__ int    wM[4][4];
    const int lane = threadIdx.x & 63, wid = threadIdx.x >> 6;
    if (lane == 0) {
        wA[wid][0] = a0; wA[wid][1] = a1; wA[wid][2] = a2; wA[wid][3] = a3;
        wM[wid][0] = m0; wM[wid][1] = m1; wM[wid][2] = m2; wM[wid][3] = m3;
    }
    __syncthreads();
    if (threadIdx.x < 4) {   // thread k handles field k
        const int k = threadIdx.x;
        double a = wA[0][k] + wA[1][k] + wA[2][k] + wA[3][k];
        int m = max(max(wM[0][k], wM[1][k]), max(wM[2][k], wM[3][k]));
        atomicAdd(&accA[img * 4 + k], a);
        atomicMax(&accM[img * 4 + k], m);
    }

    // ---- last-block finalize ----
    __threadfence();
    __shared__ int is_last;
    if (threadIdx.x == 0)
        is_last = (atomicAdd(counter, 1) == NBLK - 1) ? 1 : 0;
    __syncthreads();
    if (!is_last) return;
    __threadfence();   // acquire: all other blocks' atomics now visible

    __shared__ double sA[NF];
    __shared__ int    sM[NF];
    if (threadIdx.x < NF) {
        sA[threadIdx.x] = atomicAdd(&accA[threadIdx.x], 0.0);   // coherent read
        sM[threadIdx.x] = atomicMax(&accM[threadIdx.x], 0);
    }
    __syncthreads();
    if (threadIdx.x == 0) {
        double loss = 0.0;
        for (int g = 0; g < NIMG; ++g) {
            const double A0 = sA[g * 4 + 0], A1 = sA[g * 4 + 1];
            const double A2 = sA[g * 4 + 2], A3 = sA[g * 4 + 3];
            const int M0 = sM[g * 4 + 0], M1 = sM[g * 4 + 1];
            const int M2 = sM[g * 4 + 2], M3 = sM[g * 4 + 3];
            if (M0 > 0) { loss += A0 / (double)M0; if (M1 > 0) loss += A1 / (double)M1; }
            if (M2 > 0) { loss += A2 / (double)M2; if (M3 > 0) loss += A3 / (double)M3; }
        }
        out[0] = (float)(loss / (double)NELEM);
    }
}

extern "C" void kernel_launch(void* const* d_in, const int* in_sizes, int n_in,
                              void* d_out, int out_size, void* d_ws, size_t ws_size,
                              hipStream_t stream)
{
    const float* preds   = (const float*)d_in[0];
    const float* targets = (const float*)d_in[1];
    float* out = (float*)d_out;

    char* ws = (char*)d_ws;
    u64* bmP      = (u64*)(ws + BMP_OFF);
    u64* bmT      = (u64*)(ws + BMT_OFF);
    double* accA  = (double*)(ws + ACA_OFF);
    int*    accM  = (int*)(ws + ACM_OFF);
    int*    cnt   = (int*)(ws + CNT_OFF);

    k_bitmap<<<NIMG * 32, 256, 0, stream>>>(preds, targets, bmP, bmT, accA, accM, cnt);
    k_dtloss<<<NBLK, 256, 0, stream>>>(preds, targets, bmP, bmT, accA, accM, cnt, out);
}

// Round 8
// 81.339 us; speedup vs baseline: 1.2697x; 1.2697x over previous
//
#include <hip/hip_runtime.h>
#include <math.h>

#define HH 256
#define WW 256
#define NIMG 8            // B*C
#define NF 32             // 8 images * 4 fields
#define FLDSZ (HH * WW)
#define NELEM (NIMG * FLDSZ)
#define LARGE (1 << 27)   // sentinel d^2 when a field has no source pixels at all
#define BIGD (1 << 20)
#define BIGC (1 << 26)    // capped row-dist^2 marker (window miss / row out of range)
#define NPART 128         // row-group parts per field

// ws layout (all regions fully written before read; no memset needed):
// [0,      64KB)   u64 bmP[8][256][4]   preds fg bitmap
// [64KB,  128KB)   u64 bmT[8][256][4]   targets fg bitmap
// [128KB, 160KB)   f64 Apart[32][128]
// [160KB, 176KB)   i32 Mpart[32][128]
#define BMP_OFF 0
#define BMT_OFF (64u * 1024)
#define APA_OFF (128u * 1024)
#define MPA_OFF (160u * 1024)

typedef unsigned long long u64;

// ---- K0: per-row 256-bit fg masks for preds and targets --------------------
__global__ __launch_bounds__(256) void k_bitmap(
    const float* __restrict__ preds, const float* __restrict__ targets,
    u64* __restrict__ bmP, u64* __restrict__ bmT)
{
    const int img = blockIdx.x >> 5;
    const int rg  = blockIdx.x & 31;   // 8-row group
    const int c   = threadIdx.x;
    const int lane = c & 63, wv = c >> 6;

    const size_t ibase = ((size_t)img * HH + rg * 8) * WW;
#pragma unroll
    for (int r8 = 0; r8 < 8; ++r8) {
        float pv = preds[ibase + r8 * WW + c];
        float tv = targets[ibase + r8 * WW + c];
        u64 bp = __ballot(pv > 0.0f);   // sigmoid(x)>0.5 <=> x>0
        u64 bt = __ballot(tv > 0.5f);
        if (lane == 0) {
            const int row = rg * 8 + r8;
            bmP[((size_t)img * HH + row) * 4 + wv] = bp;
            bmT[((size_t)img * HH + row) * 4 + wv] = bt;
        }
    }
}

// windowed row-dist^2 for BOTH polarities from one set of 3 words.
// out[0] = sources are set bits (bg field), out[1] = sources are clear bits (fg field)
__device__ __forceinline__ void win_pair(const u64* __restrict__ sm, int j,
                                         int wq, int sh, int out[2])
{
    const u64 cur = sm[j * 4 + wq];
    const u64 lwr = (wq > 0) ? sm[j * 4 + wq - 1] : 0ull;
    const u64 rwr = (wq < 3) ? sm[j * 4 + wq + 1] : 0ull;
#pragma unroll
    for (int pol = 0; pol < 2; ++pol) {
        const u64 cc = pol ? ~cur : cur;
        const u64 lw = pol ? ((wq > 0) ? ~lwr : 0ull) : lwr;
        const u64 rw = pol ? ((wq < 3) ? ~rwr : 0ull) : rwr;
        u64 A = cc >> sh;
        if (sh) A |= rw << (64 - sh);
        int dR = A ? __builtin_ctzll(A) : 1000;
        u64 L = (sh == 63) ? cc : (cc & ((1ull << (sh + 1)) - 1ull));
        int dL;
        if (L)       dL = sh - (63 - __builtin_clzll(L));
        else if (lw) dL = sh + 1 + __builtin_clzll(lw);
        else         dL = 1000;
        int d = min(dR, dL);
        out[pol] = (d <= 255) ? d * d : BIGC;
    }
}

// full-row exact nearest-bit distance with optional inversion
__device__ __forceinline__ int full_rowd_f(const u64* __restrict__ sm, int j,
                                           int c, bool inv)
{
    int bestd = BIGD;
#pragma unroll
    for (int w = 0; w < 4; ++w) {
        u64 mm = sm[j * 4 + w];
        if (inv) mm = ~mm;
        if (!mm) continue;                 // wave-uniform word
        const int base = w * 64;
        int d;
        if (base + 63 < c) {
            d = c - (base + 63 - __builtin_clzll(mm));
        } else if (base > c) {
            d = base + __builtin_ctzll(mm) - c;
        } else {
            const int t = c - base;
            u64 lowm = (t == 63) ? mm : (mm & ((1ull << (t + 1)) - 1ull));
            u64 him  = mm >> t;
            int dl = lowm ? (t - (63 - __builtin_clzll(lowm))) : BIGD;
            int dr = him  ? __builtin_ctzll(him) : BIGD;
            d = min(dl, dr);
        }
        bestd = min(bestd, d);
    }
    return bestd;
}

__device__ __forceinline__ int exact_scan(const u64* __restrict__ sm, int i,
                                          int c, bool inv)
{
    int d0 = full_rowd_f(sm, i, c, inv);
    int eb = (d0 <= 255) ? d0 * d0 : LARGE;
    for (int r = 1; r < HH; ++r) {
        if (__all(r * r >= eb)) break;
        const int jd = i - r, ju = i + r;
        if (jd >= 0) {
            int d = full_rowd_f(sm, jd, c, inv);
            if (d <= 255) eb = min(eb, d * d + r * r);
        }
        if (ju < HH) {
            int d = full_rowd_f(sm, ju, c, inv);
            if (d <= 255) eb = min(eb, d * d + r * r);
        }
    }
    return eb;
}

// ---- K1: fused exact EDT^2 for all 4 fields + loss accumulation ------------
// block = (img, 2-row group): 1024 blocks x 256 threads, 16KB LDS.
__global__ __launch_bounds__(256) void k_dtloss(
    const float* __restrict__ preds, const float* __restrict__ targets,
    const u64* __restrict__ bmP, const u64* __restrict__ bmT,
    double* __restrict__ Apart, int* __restrict__ Mpart)
{
    const int img = blockIdx.x >> 7;    // 8 images
    const int rg  = blockIdx.x & 127;   // 2-row group
    const int c   = threadIdx.x;
    const int wq  = c >> 6, sh = c & 63;

    __shared__ u64 sp[HH * 4];   // preds fg bitmap (raw)
    __shared__ u64 st[HH * 4];   // targets fg bitmap (raw)

#pragma unroll
    for (int q = 0; q < 4; ++q) {
        sp[q * 256 + c] = bmP[(size_t)img * HH * 4 + q * 256 + c];
        st[q * 256 + c] = bmT[(size_t)img * HH * 4 + q * 256 + c];
    }
    __syncthreads();

    const int i0 = rg * 2;

    float xs[2], ts[2];
#pragma unroll
    for (int ii = 0; ii < 2; ++ii) {
        const size_t idx = ((size_t)img * HH + i0 + ii) * WW + c;
        xs[ii] = preds[idx];
        ts[ii] = targets[idx];
    }

    // rolling 9-row windows: f0=p_fg(inv) f1=p_bg f2=t_fg(inv) f3=t_bg
    int wPf[9], wPb[9], wTf[9], wTb[9];
#pragma unroll
    for (int q = 0; q < 9; ++q) {
        const int j = i0 - 4 + q;
        if ((unsigned)j < HH) {
            int prP[2], prT[2];
            win_pair(sp, j, wq, sh, prP);
            win_pair(st, j, wq, sh, prT);
            wPb[q] = prP[0]; wPf[q] = prP[1];
            wTb[q] = prT[0]; wTf[q] = prT[1];
        } else {
            wPb[q] = BIGC; wPf[q] = BIGC; wTb[q] = BIGC; wTf[q] = BIGC;
        }
    }

    double a0 = 0.0, a1 = 0.0, a2 = 0.0, a3 = 0.0;
    int m0 = 0, m1 = 0, m2 = 0, m3 = 0;

#pragma unroll
    for (int ii = 0; ii < 2; ++ii) {
        const int i = i0 + ii;

#define COMBINE(w) ({                                             \
        int _b = w[4];                                            \
        _b = min(_b, min(w[3], w[5]) + 1);                        \
        _b = min(_b, min(w[2], w[6]) + 4);                        \
        _b = min(_b, min(w[1], w[7]) + 9);                        \
        _b = min(_b, min(w[0], w[8]) + 16); _b; })

        int b0 = COMBINE(wPf);
        int b1 = COMBINE(wPb);
        int b2 = COMBINE(wTf);
        int b3 = COMBINE(wTb);

        if (__any(max(max(b0, b1), max(b2, b3)) > 16)) {   // rare exact fallback
            if (__any(b0 > 16)) b0 = exact_scan(sp, i, c, true);
            if (__any(b1 > 16)) b1 = exact_scan(sp, i, c, false);
            if (__any(b2 > 16)) b2 = exact_scan(st, i, c, true);
            if (__any(b3 > 16)) b3 = exact_scan(st, i, c, false);
        }

        float p   = 1.0f / (1.0f + expf(-xs[ii]));
        float err = (p - ts[ii]) * (p - ts[ii]);
        const double de = (double)err;
        a0 += de * (double)b0;  a1 += de * (double)b1;
        a2 += de * (double)b2;  a3 += de * (double)b3;
        m0 = max(m0, b0); m1 = max(m1, b1); m2 = max(m2, b2); m3 = max(m3, b3);

#pragma unroll
        for (int q = 0; q < 8; ++q) {
            wPf[q] = wPf[q + 1]; wPb[q] = wPb[q + 1];
            wTf[q] = wTf[q + 1]; wTb[q] = wTb[q + 1];
        }
        const int jn = i + 5;
        if ((unsigned)jn < HH) {
            int prP[2], prT[2];
            win_pair(sp, jn, wq, sh, prP);
            win_pair(st, jn, wq, sh, prT);
            wPb[8] = prP[0]; wPf[8] = prP[1];
            wTb[8] = prT[0]; wTf[8] = prT[1];
        } else {
            wPb[8] = BIGC; wPf[8] = BIGC; wTb[8] = BIGC; wTf[8] = BIGC;
        }
    }

    // block reduction (4 waves)
#pragma unroll
    for (int off = 32; off > 0; off >>= 1) {
        a0 += __shfl_down(a0, off); a1 += __shfl_down(a1, off);
        a2 += __shfl_down(a2, off); a3 += __shfl_down(a3, off);
        m0 = max(m0, __shfl_down(m0, off)); m1 = max(m1, __shfl_down(m1, off));
        m2 = max(m2, __shfl_down(m2, off)); m3 = max(m3, __shfl_down(m3, off));
    }
    __shared__ double wA[4][4];
    __shared__ int    wM[4][4];
    const int lane = threadIdx.x & 63, wid = threadIdx.x >> 6;
    if (lane == 0) {
        wA[wid][0] = a0; wA[wid][1] = a1; wA[wid][2] = a2; wA[wid][3] = a3;
        wM[wid][0] = m0; wM[wid][1] = m1; wM[wid][2] = m2; wM[wid][3] = m3;
    }
    __syncthreads();
    if (threadIdx.x < 4) {   // thread k handles field k
        const int k = threadIdx.x;
        double a = wA[0][k] + wA[1][k] + wA[2][k] + wA[3][k];
        int m = max(max(wM[0][k], wM[1][k]), max(wM[2][k], wM[3][k]));
        Apart[(size_t)(img * 4 + k) * NPART + rg] = a;
        Mpart[(size_t)(img * 4 + k) * NPART + rg] = m;
    }
}

// ---- K2: final reduce + gating + normalize ---------------------------------
__global__ __launch_bounds__(1024) void k_final3(
    const double* __restrict__ Apart, const int* __restrict__ Mpart,
    float* __restrict__ out)
{
    const int lane = threadIdx.x & 63, wave = threadIdx.x >> 6;  // 16 waves
    __shared__ double sA[NF];
    __shared__ int    sM[NF];
#pragma unroll
    for (int rep = 0; rep < 2; ++rep) {
        const int f = wave * 2 + rep;       // 0..31
        double v = Apart[f * NPART + lane] + Apart[f * NPART + 64 + lane];
        int m = max(Mpart[f * NPART + lane], Mpart[f * NPART + 64 + lane]);
#pragma unroll
        for (int off = 32; off > 0; off >>= 1) {
            v += __shfl_down(v, off);
            m = max(m, __shfl_down(m, off));
        }
        if (lane == 0) { sA[f] = v; sM[f] = m; }
    }
    __syncthreads();
    if (threadIdx.x == 0) {
        double loss = 0.0;
        for (int g = 0; g < NIMG; ++g) {
            const double A0 = sA[g * 4 + 0], A1 = sA[g * 4 + 1];
            const double A2 = sA[g * 4 + 2], A3 = sA[g * 4 + 3];
            const int M0 = sM[g * 4 + 0], M1 = sM[g * 4 + 1];
            const int M2 = sM[g * 4 + 2], M3 = sM[g * 4 + 3];
            if (M0 > 0) { loss += A0 / (double)M0; if (M1 > 0) loss += A1 / (double)M1; }
            if (M2 > 0) { loss += A2 / (double)M2; if (M3 > 0) loss += A3 / (double)M3; }
        }
        out[0] = (float)(loss / (double)NELEM);
    }
}

extern "C" void kernel_launch(void* const* d_in, const int* in_sizes, int n_in,
                              void* d_out, int out_size, void* d_ws, size_t ws_size,
                              hipStream_t stream)
{
    const float* preds   = (const float*)d_in[0];
    const float* targets = (const float*)d_in[1];
    float* out = (float*)d_out;

    char* ws = (char*)d_ws;
    u64* bmP      = (u64*)(ws + BMP_OFF);
    u64* bmT      = (u64*)(ws + BMT_OFF);
    double* Apart = (double*)(ws + APA_OFF);
    int*    Mpart = (int*)(ws + MPA_OFF);

    k_bitmap<<<NIMG * 32, 256, 0, stream>>>(preds, targets, bmP, bmT);
    k_dtloss<<<NIMG * NPART, 256, 0, stream>>>(preds, targets, bmP, bmT, Apart, Mpart);
    k_final3<<<1, 1024, 0, stream>>>(Apart, Mpart, out);
}

// Round 10
// 75.214 us; speedup vs baseline: 1.3731x; 1.0814x over previous
//
#include <hip/hip_runtime.h>
#include <math.h>

#define HH 256
#define WW 256
#define NIMG 8            // B*C
#define NF 32             // 8 images * 4 fields
#define FLDSZ (HH * WW)
#define NELEM (NIMG * FLDSZ)
#define LARGE (1 << 27)   // sentinel d^2 when a field has no source pixels at all
#define BIGD (1 << 20)
#define BIGC (1 << 26)    // capped row-dist^2 marker (window miss / row out of range)

// ws layout (all regions fully written before read; no memset needed):
// [0,      64KB)   u64 bmP[8][256][4]   preds fg bitmap
// [64KB,  128KB)   u64 bmT[8][256][4]   targets fg bitmap
// [128KB, 132KB)   f64 Apart[512]
// [132KB, 134KB)   i32 Mpart[512]
#define BMP_OFF 0
#define BMT_OFF (64u * 1024)
#define APA_OFF (128u * 1024)
#define MPA_OFF (132u * 1024)

typedef unsigned long long u64;

// ---- K0: per-row 256-bit fg masks for preds and targets --------------------
__global__ __launch_bounds__(256) void k_bitmap(
    const float* __restrict__ preds, const float* __restrict__ targets,
    u64* __restrict__ bmP, u64* __restrict__ bmT)
{
    const int img = blockIdx.x >> 5;   // 8 images
    const int rg  = blockIdx.x & 31;   // 8-row group
    const int c   = threadIdx.x;
    const int lane = c & 63, wv = c >> 6;

    const size_t ibase = ((size_t)img * HH + rg * 8) * WW;
#pragma unroll
    for (int r8 = 0; r8 < 8; ++r8) {
        float pv = preds[ibase + r8 * WW + c];
        float tv = targets[ibase + r8 * WW + c];
        u64 bp = __ballot(pv > 0.0f);   // sigmoid(x)>0.5 <=> x>0
        u64 bt = __ballot(tv > 0.5f);
        if (lane == 0) {
            const int row = rg * 8 + r8;
            bmP[((size_t)img * HH + row) * 4 + wv] = bp;
            bmT[((size_t)img * HH + row) * 4 + wv] = bt;
        }
    }
}

// ---- row-distance helpers (sources = set bits in staged bitmap) ------------
// Windowed: exact if nearest source in row j is within ~63 cols, else BIGC.
__device__ __forceinline__ int win_rowd2(const u64* __restrict__ sbm,
                                         int j, int wq, int sh)
{
    u64 cur = sbm[j * 4 + wq];
    u64 lw  = (wq > 0) ? sbm[j * 4 + wq - 1] : 0ull;
    u64 rw  = (wq < 3) ? sbm[j * 4 + wq + 1] : 0ull;
    u64 A = cur >> sh;              // bit k = global col c+k
    if (sh) A |= rw << (64 - sh);
    int dR = A ? __builtin_ctzll(A) : 1000;
    u64 L = (sh == 63) ? cur : (cur & ((1ull << (sh + 1)) - 1ull));
    int dL;
    if (L)       dL = sh - (63 - __builtin_clzll(L));
    else if (lw) dL = sh + 1 + __builtin_clzll(lw);
    else         dL = 1000;
    int d = min(dR, dL);
    return (d <= 255) ? d * d : BIGC;
}

// Full 4-word exact nearest-bit distance (lattice dist, BIGD if empty row).
__device__ __forceinline__ int full_rowd(const u64* __restrict__ sbm,
                                         int j, int c)
{
    int bestd = BIGD;
#pragma unroll
    for (int w = 0; w < 4; ++w) {
        u64 mm = sbm[j * 4 + w];   // wave-uniform word
        if (!mm) continue;
        const int base = w * 64;
        int d;
        if (base + 63 < c) {
            d = c - (base + 63 - __builtin_clzll(mm));
        } else if (base > c) {
            d = base + __builtin_ctzll(mm) - c;
        } else {
            const int t = c - base;
            u64 lowm = (t == 63) ? mm : (mm & ((1ull << (t + 1)) - 1ull));
            u64 him  = mm >> t;
            int dl = lowm ? (t - (63 - __builtin_clzll(lowm))) : BIGD;
            int dr = him  ? __builtin_ctzll(him) : BIGD;
            d = min(dl, dr);
        }
        bestd = min(bestd, d);
    }
    return bestd;
}

// ---- K1: fused exact 2D EDT^2 + loss accumulation per field ----------------
// block = (field, 16-row group). LDS: inverted-as-needed bitmap (8 KB).
__global__ __launch_bounds__(256) void k_dtloss(
    const float* __restrict__ preds, const float* __restrict__ targets,
    const u64* __restrict__ bmP,
    const u64* __restrict__ bmT,
    double* __restrict__ Apart, int* __restrict__ Mpart)
{
    const int f   = blockIdx.x >> 4;    // field 0..31
    const int rg  = blockIdx.x & 15;    // 16-row group
    const int img = f >> 2;
    const int k   = f & 3;              // 0:p_fg 1:p_bg 2:t_fg 3:t_bg
    const int c   = threadIdx.x;
    const int wq  = c >> 6, sh = c & 63;

    __shared__ u64 sbm[HH * 4];   // sources = set bits

    const u64* g = (k < 2) ? (bmP + (size_t)img * HH * 4)
                           : (bmT + (size_t)img * HH * 4);
    const bool inv = ((k & 1) == 0);    // fg field: sources are NON-mask pixels
#pragma unroll
    for (int q = 0; q < 4; ++q) {
        u64 w = g[q * 256 + c];
        sbm[q * 256 + c] = inv ? ~w : w;
    }
    __syncthreads();

    const int i0 = rg * 16;
    int rw9[9];
#pragma unroll
    for (int q = 0; q < 9; ++q) {
        const int j = i0 - 4 + q;
        rw9[q] = ((unsigned)j < HH) ? win_rowd2(sbm, j, wq, sh) : BIGC;
    }

    double accA = 0.0;
    int mx = 0;

    for (int ii = 0; ii < 16; ++ii) {
        const int i = i0 + ii;

        int best = rw9[4];
        best = min(best, min(rw9[3], rw9[5]) + 1);
        best = min(best, min(rw9[2], rw9[6]) + 4);
        best = min(best, min(rw9[1], rw9[7]) + 9);
        best = min(best, min(rw9[0], rw9[8]) + 16);

        if (__any(best > 16)) {
            // exact fallback (rare): adaptive outward scan with full row dist
            int d0 = full_rowd(sbm, i, c);
            int eb = (d0 <= 255) ? d0 * d0 : LARGE;
            for (int r = 1; r < HH; ++r) {
                if (__all(r * r >= eb)) break;
                const int jd = i - r, ju = i + r;
                if (jd >= 0) {
                    int d = full_rowd(sbm, jd, c);
                    if (d <= 255) eb = min(eb, d * d + r * r);
                }
                if (ju < HH) {
                    int d = full_rowd(sbm, ju, c);
                    if (d <= 255) eb = min(eb, d * d + r * r);
                }
            }
            best = eb;
        }

        // fused loss term: err(pixel) * d^2
        const size_t idx = ((size_t)img * HH + i) * WW + c;
        float x = preds[idx];
        float t = targets[idx];
        float p = 1.0f / (1.0f + expf(-x));
        float err = (p - t) * (p - t);
        accA += (double)err * (double)best;
        mx = max(mx, best);

        // shift window, fetch row i+5
#pragma unroll
        for (int q = 0; q < 8; ++q) rw9[q] = rw9[q + 1];
        const int jn = i + 5;
        rw9[8] = ((unsigned)jn < HH) ? win_rowd2(sbm, jn, wq, sh) : BIGC;
    }

    // block reduction (4 waves)
#pragma unroll
    for (int off = 32; off > 0; off >>= 1) {
        accA += __shfl_down(accA, off);
        mx = max(mx, __shfl_down(mx, off));
    }
    __shared__ double wA[4];
    __shared__ int    wM[4];
    const int lane = threadIdx.x & 63, wid = threadIdx.x >> 6;
    if (lane == 0) { wA[wid] = accA; wM[wid] = mx; }
    __syncthreads();
    if (threadIdx.x == 0) {
        double a = wA[0] + wA[1] + wA[2] + wA[3];
        int m = max(max(wM[0], wM[1]), max(wM[2], wM[3]));
        Apart[blockIdx.x] = a;
        Mpart[blockIdx.x] = m;
    }
}

// ---- K2: final reduce + gating + normalize ---------------------------------
__global__ __launch_bounds__(512) void k_final2(
    const double* __restrict__ Apart, const int* __restrict__ Mpart,
    float* __restrict__ out)
{
    const int t = threadIdx.x;          // 512 = 32 fields * 16 parts
    double v = Apart[t];
    int m = Mpart[t];
#pragma unroll
    for (int off = 8; off > 0; off >>= 1) {    // segments of 16 (wave-aligned)
        v += __shfl_down(v, off);
        m = max(m, __shfl_down(m, off));
    }
    __shared__ double sA[NF];
    __shared__ int    sM[NF];
    if ((t & 15) == 0) { sA[t >> 4] = v; sM[t >> 4] = m; }
    __syncthreads();
    if (t == 0) {
        double loss = 0.0;
        for (int img = 0; img < NIMG; ++img) {
            const double a0 = sA[img * 4 + 0], a1 = sA[img * 4 + 1];
            const double a2 = sA[img * 4 + 2], a3 = sA[img * 4 + 3];
            const int m0 = sM[img * 4 + 0], m1 = sM[img * 4 + 1];
            const int m2 = sM[img * 4 + 2], m3 = sM[img * 4 + 3];
            if (m0 > 0) { loss += a0 / (double)m0; if (m1 > 0) loss += a1 / (double)m1; }
            if (m2 > 0) { loss += a2 / (double)m2; if (m3 > 0) loss += a3 / (double)m3; }
        }
        out[0] = (float)(loss / (double)NELEM);
    }
}

extern "C" void kernel_launch(void* const* d_in, const int* in_sizes, int n_in,
                              void* d_out, int out_size, void* d_ws, size_t ws_size,
                              hipStream_t stream)
{
    const float* preds   = (const float*)d_in[0];
    const float* targets = (const float*)d_in[1];
    float* out = (float*)d_out;

    char* ws = (char*)d_ws;
    u64* bmP      = (u64*)(ws + BMP_OFF);
    u64* bmT      = (u64*)(ws + BMT_OFF);
    double* Apart = (double*)(ws + APA_OFF);
    int*    Mpart = (int*)(ws + MPA_OFF);

    k_bitmap<<<NIMG * 32, 256, 0, stream>>>(preds, targets, bmP, bmT);
    k_dtloss<<<NF * 16,   256, 0, stream>>>(preds, targets, bmP, bmT, Apart, Mpart);
    k_final2<<<1,         512, 0, stream>>>(Apart, Mpart, out);
}